// Round 10
// baseline (634.621 us; speedup 1.0000x reference)
//
#include <hip/hip_runtime.h>
#include <stdint.h>

typedef unsigned short u16;
typedef __bf16 bf16x8 __attribute__((ext_vector_type(8)));
typedef float f32x4 __attribute__((ext_vector_type(4)));

#define DEV __device__ __forceinline__

DEV float bf2f(u16 u) {
    union { uint32_t u; float f; } c; c.u = ((uint32_t)u) << 16; return c.f;
}
DEV u16 f2bf(float f) {
    union { float f; uint32_t u; } c; c.f = f;
    uint32_t u = c.u;
    u += 0x7FFFu + ((u >> 16) & 1u);   // round-to-nearest-even
    return (u16)(u >> 16);
}

DEV void gload_lds16(const u16* gp, u16* lp) {
    __builtin_amdgcn_global_load_lds(
        (__attribute__((address_space(1))) u16*)(uintptr_t)gp,
        (__attribute__((address_space(3))) u16*)lp,
        16, 0, 0);
}

#define WAITVM6 asm volatile("s_waitcnt vmcnt(6)" ::: "memory")
#define WAITVM4 asm volatile("s_waitcnt vmcnt(4)" ::: "memory")
#define WAITVM0 asm volatile("s_waitcnt vmcnt(0)" ::: "memory")
#define MEMFENCE asm volatile("" ::: "memory")

// ---- 16-bf16 (32B) helpers -------------------------------------------------
DEV void load16f(const u16* p, float* f) {
    uint4 a = *reinterpret_cast<const uint4*>(p);
    uint4 b = *reinterpret_cast<const uint4*>(p + 8);
    uint32_t w[8] = { a.x, a.y, a.z, a.w, b.x, b.y, b.z, b.w };
#pragma unroll
    for (int k = 0; k < 8; ++k) {
        union { uint32_t u; float f; } lo, hi;
        lo.u = w[k] << 16; hi.u = w[k] & 0xFFFF0000u;
        f[2 * k] = lo.f; f[2 * k + 1] = hi.f;
    }
}
DEV float dot16(const u16* p, const float* q) {
    uint4 a = *reinterpret_cast<const uint4*>(p);
    uint4 b = *reinterpret_cast<const uint4*>(p + 8);
    uint32_t w[8] = { a.x, a.y, a.z, a.w, b.x, b.y, b.z, b.w };
    float d = 0.0f;
#pragma unroll
    for (int k = 0; k < 8; ++k) {
        union { uint32_t u; float f; } lo, hi;
        lo.u = w[k] << 16; hi.u = w[k] & 0xFFFF0000u;
        d += q[2 * k] * lo.f;
        d += q[2 * k + 1] * hi.f;
    }
    return d;
}
DEV void fma16(const u16* p, float pw, float* acc) {
    uint4 a = *reinterpret_cast<const uint4*>(p);
    uint4 b = *reinterpret_cast<const uint4*>(p + 8);
    uint32_t w[8] = { a.x, a.y, a.z, a.w, b.x, b.y, b.z, b.w };
#pragma unroll
    for (int k = 0; k < 8; ++k) {
        union { uint32_t u; float f; } lo, hi;
        lo.u = w[k] << 16; hi.u = w[k] & 0xFFFF0000u;
        acc[2 * k] += pw * lo.f;
        acc[2 * k + 1] += pw * hi.f;
    }
}
DEV void store16(u16* p, const float* y) {
    uint32_t w[8];
#pragma unroll
    for (int k = 0; k < 8; ++k)
        w[k] = (uint32_t)f2bf(y[2 * k]) | ((uint32_t)f2bf(y[2 * k + 1]) << 16);
    uint4 a = { w[0], w[1], w[2], w[3] };
    uint4 b = { w[4], w[5], w[6], w[7] };
    *reinterpret_cast<uint4*>(p) = a;
    *reinterpret_cast<uint4*>(p + 8) = b;
}

// ---------------------------------------------------------------- convert
__global__ __launch_bounds__(256) void k_f32_to_bf16(
    const float* __restrict__ in, u16* __restrict__ out, int n4)
{
    int i = blockIdx.x * 256 + threadIdx.x;
    if (i >= n4) return;
    float4 v = reinterpret_cast<const float4*>(in)[i];
    ushort4 o;
    o.x = f2bf(v.x); o.y = f2bf(v.y); o.z = f2bf(v.z); o.w = f2bf(v.w);
    reinterpret_cast<ushort4*>(out)[i] = o;
}

// all 6 weight tensors -> one contiguous bf16 region (compile-time boundaries)
__global__ __launch_bounds__(256) void k_convw(
    const float* __restrict__ s0, const float* __restrict__ s1,
    const float* __restrict__ s2, const float* __restrict__ s3,
    const float* __restrict__ s4, const float* __restrict__ s5,
    u16* __restrict__ out)
{
    const int i = blockIdx.x * 256 + threadIdx.x;   // f32x4 index, grid exact
    const float4* src;
    int off;
    if      (i <  196608) { src = (const float4*)s0; off = i; }
    else if (i <  262144) { src = (const float4*)s1; off = i - 196608; }
    else if (i <  458752) { src = (const float4*)s2; off = i - 262144; }
    else if (i <  524288) { src = (const float4*)s3; off = i - 458752; }
    else if (i <  786432) { src = (const float4*)s4; off = i - 524288; }
    else                  { src = (const float4*)s5; off = i - 786432; }
    float4 v = src[off];
    ushort4 o;
    o.x = f2bf(v.x); o.y = f2bf(v.y); o.z = f2bf(v.z); o.w = f2bf(v.w);
    reinterpret_cast<ushort4*>(out)[i] = o;
}

// ---------------------------------------------------------------- GEMM 8-phase
// 256x256 tile, BK=64, 512 thr = 8 waves (2M x 4N), per-wave 128x64.
// Used for qkv (N=1536) and FFN1 (N=2048).
template<bool RELU, bool RESID, int NT>
__global__ __launch_bounds__(512, 2) void k_gemm8p(
    const u16* __restrict__ A, const u16* __restrict__ W,
    const float* __restrict__ bias, const u16* __restrict__ res,
    u16* __restrict__ C, int M, int N, int K)
{
    __shared__ __align__(16) u16 Abuf[2][16384];
    __shared__ __align__(16) u16 Bbuf[2][16384];

    const int tid  = threadIdx.x;
    const int lane = tid & 63;
    const int wave = tid >> 6;
    const int wm   = wave >> 2;
    const int wn   = wave & 3;
    const int l15  = lane & 15;
    const int lg   = lane >> 4;

    const int nwg = gridDim.x;
    const int v = (blockIdx.x & 7) * (nwg >> 3) + (blockIdx.x >> 3);
    const long tileM = (long)(v / NT) * 256;
    const long tileN = (long)(v % NT) * 256;

    const int nIter = K >> 7;

    f32x4 acc[8][4] = {};

    const long Abase = (tileM + (tid >> 3)) * (long)K + (((tid & 7) ^ ((tid >> 3) & 7)) << 3);
    const long Bbase = (tileN + (tid >> 3)) * (long)K + (((tid & 7) ^ ((tid >> 3) & 7)) << 3);

    auto stA = [&](int h, int t) {
#pragma unroll
        for (int e = 0; e < 2; ++e)
            gload_lds16(A + Abase + (long)(h * 128 + e * 64) * K + t * 64,
                        &Abuf[t & 1][(h * 1024 + e * 512 + tid) * 8]);
    };
    auto stB = [&](int h, int t) {
#pragma unroll
        for (int e = 0; e < 2; ++e)
            gload_lds16(W + Bbase + (long)(h * 128 + e * 64) * K + t * 64,
                        &Bbuf[t & 1][(h * 1024 + e * 512 + tid) * 8]);
    };

    int koff[2];
#pragma unroll
    for (int ks = 0; ks < 2; ++ks)
        koff[ks] = ((ks * 4 + lg) ^ (l15 & 7)) * 8;
    const int aRow = wm * 128 + l15;
    const int bRow = wn * 64 + l15;

    stA(0, 0); stA(1, 0); stB(0, 0); stB(1, 0); stB(0, 1); stB(1, 1);
    WAITVM4;
    MEMFENCE;
    __builtin_amdgcn_s_barrier();
    MEMFENCE;

    bf16x8 b[4][2];

    for (int j = 0; j < nIter; ++j) {
        const bool pre = (j + 1 < nIter);
        const int E = 2 * j;
#pragma unroll
        for (int ph = 0; ph < 8; ++ph) {
            const int bb = ph >> 2;
            const int q  = ph & 3;
            if (q == 0) {
#pragma unroll
                for (int n = 0; n < 4; ++n)
#pragma unroll
                    for (int ks = 0; ks < 2; ++ks)
                        b[n][ks] = *reinterpret_cast<const bf16x8*>(
                            &Bbuf[bb][(bRow + n * 16) * 64 + koff[ks]]);
            }
            bf16x8 aq[2][2];
#pragma unroll
            for (int mi = 0; mi < 2; ++mi)
#pragma unroll
                for (int ks = 0; ks < 2; ++ks)
                    aq[mi][ks] = *reinterpret_cast<const bf16x8*>(
                        &Abuf[bb][(aRow + (q * 2 + mi) * 16) * 64 + koff[ks]]);
            if (ph == 0) stA(0, E + 1);
            else if (ph == 1) stA(1, E + 1);
            else if (ph == 2) { if (pre) stB(0, E + 2); }
            else if (ph == 3) {
                if (pre) { stB(1, E + 2); WAITVM4; } else { WAITVM0; }
            }
            else if (ph == 4) { if (pre) stA(0, E + 2); }
            else if (ph == 5) { if (pre) stA(1, E + 2); }
            else if (ph == 6) { if (pre) stB(0, E + 3); }
            else {
                if (pre) { stB(1, E + 3); WAITVM4; } else { WAITVM0; }
            }
            MEMFENCE;
            __builtin_amdgcn_s_barrier();
            MEMFENCE;
            __builtin_amdgcn_s_setprio(1);
#pragma unroll
            for (int mi = 0; mi < 2; ++mi)
#pragma unroll
                for (int n = 0; n < 4; ++n)
#pragma unroll
                    for (int ks = 0; ks < 2; ++ks)
                        acc[q * 2 + mi][n] = __builtin_amdgcn_mfma_f32_16x16x32_bf16(
                            aq[mi][ks], b[n][ks], acc[q * 2 + mi][n], 0, 0, 0);
            __builtin_amdgcn_s_setprio(0);
            MEMFENCE;
            __builtin_amdgcn_s_barrier();
            MEMFENCE;
        }
    }

    const int crow0 = (int)tileM + wm * 128 + ((lane >> 4) << 2);
    const int ccol0 = (int)tileN + wn * 64 + l15;
#pragma unroll
    for (int m = 0; m < 8; ++m) {
#pragma unroll
        for (int n = 0; n < 4; ++n) {
            const int col = ccol0 + n * 16;
            const float bv = bias[col];
#pragma unroll
            for (int r = 0; r < 4; ++r) {
                const long row = crow0 + m * 16 + r;
                float vv = acc[m][n][r] + bv;
                if (RESID) vv += bf2f(res[row * N + col]);
                if (RELU)  vv = fmaxf(vv, 0.0f);
                C[row * N + col] = f2bf(vv);
            }
        }
    }
}

// ---------------------------------------------------------------- GEMM 3-slot
// BM=256, BN=128, BK=64, 8 waves (4M x 2N). Used for proj (K=512).
template<bool RELU, bool RESID, int NT>
__global__ __launch_bounds__(512, 2) void k_gemm3s(
    const u16* __restrict__ A, const u16* __restrict__ W,
    const float* __restrict__ bias, const u16* __restrict__ res,
    u16* __restrict__ C, int M, int N, int K)
{
    __shared__ __align__(16) u16 Abuf[3][16384];
    __shared__ __align__(16) u16 Bbuf[3][8192];

    const int tid  = threadIdx.x;
    const int lane = tid & 63;
    const int wave = tid >> 6;
    const int wm   = wave >> 1;
    const int wn   = wave & 1;
    const int l15  = lane & 15;
    const int lg   = lane >> 4;

    const int nwg = gridDim.x;
    const int v = (blockIdx.x & 7) * (nwg >> 3) + (blockIdx.x >> 3);
    const long tileM = (long)(v / NT) * 256;
    const long tileN = (long)(v % NT) * 128;

    const int nT = K >> 6;

    f32x4 acc[4][4] = {};

    const long Abase = (tileM + (tid >> 3)) * (long)K + (((tid & 7) ^ ((tid >> 3) & 7)) << 3);
    const long Bbase = (tileN + (tid >> 3)) * (long)K + (((tid & 7) ^ ((tid >> 3) & 7)) << 3);

    auto stage = [&](int t, int p) {
        const int s = t % 3;
        const long ko = (long)t * 64;
        if (p == 0) {
#pragma unroll
            for (int e = 0; e < 3; ++e)
                gload_lds16(A + Abase + (long)(e * 64) * K + ko,
                            &Abuf[s][(e * 512 + tid) * 8]);
        } else {
            gload_lds16(A + Abase + (long)192 * K + ko,
                        &Abuf[s][(3 * 512 + tid) * 8]);
#pragma unroll
            for (int e = 0; e < 2; ++e)
                gload_lds16(W + Bbase + (long)(e * 64) * K + ko,
                            &Bbuf[s][(e * 512 + tid) * 8]);
        }
    };

    int koff[2];
#pragma unroll
    for (int ks = 0; ks < 2; ++ks)
        koff[ks] = ((ks * 4 + lg) ^ (l15 & 7)) * 8;
    const int aRow = wm * 64 + l15;
    const int bRow = wn * 64 + l15;

    stage(0, 0); stage(0, 1);
    stage(1, 0); stage(1, 1);
    WAITVM6;
    MEMFENCE;
    __builtin_amdgcn_s_barrier();
    MEMFENCE;

    for (int j = 0; j < nT; ++j) {
        const int s = j % 3;
        const u16* ab = Abuf[s];
        const u16* bb = Bbuf[s];
        const bool pre = (j + 2 < nT);

        bf16x8 bfr[4][2];
#pragma unroll
        for (int n = 0; n < 4; ++n)
#pragma unroll
            for (int ks = 0; ks < 2; ++ks)
                bfr[n][ks] = *reinterpret_cast<const bf16x8*>(
                    &bb[(bRow + n * 16) * 64 + koff[ks]]);
        bf16x8 a0[2][2];
#pragma unroll
        for (int mi = 0; mi < 2; ++mi)
#pragma unroll
            for (int ks = 0; ks < 2; ++ks)
                a0[mi][ks] = *reinterpret_cast<const bf16x8*>(
                    &ab[(aRow + mi * 16) * 64 + koff[ks]]);
        if (pre) stage(j + 2, 0);
        MEMFENCE;
        __builtin_amdgcn_s_barrier();
        MEMFENCE;
        __builtin_amdgcn_s_setprio(1);
#pragma unroll
        for (int mi = 0; mi < 2; ++mi)
#pragma unroll
            for (int n = 0; n < 4; ++n)
#pragma unroll
                for (int ks = 0; ks < 2; ++ks)
                    acc[mi][n] = __builtin_amdgcn_mfma_f32_16x16x32_bf16(
                        a0[mi][ks], bfr[n][ks], acc[mi][n], 0, 0, 0);
        __builtin_amdgcn_s_setprio(0);
        MEMFENCE;
        __builtin_amdgcn_s_barrier();
        MEMFENCE;

        bf16x8 a1[2][2];
#pragma unroll
        for (int mi = 0; mi < 2; ++mi)
#pragma unroll
            for (int ks = 0; ks < 2; ++ks)
                a1[mi][ks] = *reinterpret_cast<const bf16x8*>(
                    &ab[(aRow + (2 + mi) * 16) * 64 + koff[ks]]);
        if (pre) { stage(j + 2, 1); WAITVM6; }
        else if (j + 1 < nT) { WAITVM0; }
        MEMFENCE;
        __builtin_amdgcn_s_barrier();
        MEMFENCE;
        __builtin_amdgcn_s_setprio(1);
#pragma unroll
        for (int mi = 0; mi < 2; ++mi)
#pragma unroll
            for (int n = 0; n < 4; ++n)
#pragma unroll
                for (int ks = 0; ks < 2; ++ks)
                    acc[2 + mi][n] = __builtin_amdgcn_mfma_f32_16x16x32_bf16(
                        a1[mi][ks], bfr[n][ks], acc[2 + mi][n], 0, 0, 0);
        __builtin_amdgcn_s_setprio(0);
        MEMFENCE;
        __builtin_amdgcn_s_barrier();
        MEMFENCE;
    }

    const int crow0 = (int)tileM + wm * 64 + ((lane >> 4) << 2);
    const int ccol0 = (int)tileN + wn * 64 + l15;
#pragma unroll
    for (int m = 0; m < 4; ++m) {
#pragma unroll
        for (int n = 0; n < 4; ++n) {
            const int col = ccol0 + n * 16;
            const float bv = bias[col];
#pragma unroll
            for (int r = 0; r < 4; ++r) {
                const long row = crow0 + m * 16 + r;
                float vv = acc[m][n][r] + bv;
                if (RESID) vv += bf2f(res[row * N + col]);
                if (RELU)  vv = fmaxf(vv, 0.0f);
                C[row * N + col] = f2bf(vv);
            }
        }
    }
}

// ---------------------------------------------------------------- GEMM 2-block
// BM=128, BN=64, BK=64, 256 thr = 4 waves (2M x 2N), per-wave 64x32.
// 3-slot ring (72 KB LDS -> 2 blocks/CU: two independent barrier domains),
// counted vmcnt(6), pre-swizzled staging. Used for FFN2 (N=512, K=2048).
// Stage: part0 = A rows 0..95 (3 gloads), part1 = A rows 96..127 + B (3).
template<bool RELU, bool RESID, int NT>
__global__ __launch_bounds__(256, 2) void k_gemm2b(
    const u16* __restrict__ A, const u16* __restrict__ W,
    const float* __restrict__ bias, const u16* __restrict__ res,
    u16* __restrict__ C, int M, int N, int K)
{
    __shared__ __align__(16) u16 Abuf[3][8192];   // 128 x 64 per slot
    __shared__ __align__(16) u16 Bbuf[3][4096];   // 64 x 64 per slot

    const int tid  = threadIdx.x;
    const int lane = tid & 63;
    const int wave = tid >> 6;     // 0..3
    const int wm   = wave >> 1;    // 0..1
    const int wn   = wave & 1;     // 0..1
    const int l15  = lane & 15;
    const int lg   = lane >> 4;

    const int nwg = gridDim.x;     // divisible by 8
    const int v = (blockIdx.x & 7) * (nwg >> 3) + (blockIdx.x >> 3);
    const long tileM = (long)(v / NT) * 128;
    const long tileN = (long)(v % NT) * 64;

    const int nT = K >> 6;

    f32x4 acc[4][2] = {};

    // staging: 8 threads/row (row = tid>>3, chunk = tid&7 pre-swizzled)
    const long Abase = (tileM + (tid >> 3)) * (long)K + (((tid & 7) ^ ((tid >> 3) & 7)) << 3);
    const long Bbase = (tileN + (tid >> 3)) * (long)K + (((tid & 7) ^ ((tid >> 3) & 7)) << 3);

    auto stage = [&](int t, int p) {
        const int s = t % 3;
        const long ko = (long)t * 64;
        if (p == 0) {
#pragma unroll
            for (int e = 0; e < 3; ++e)
                gload_lds16(A + Abase + (long)(e * 32) * K + ko,
                            &Abuf[s][(e * 256 + tid) * 8]);
        } else {
            gload_lds16(A + Abase + (long)96 * K + ko,
                        &Abuf[s][(3 * 256 + tid) * 8]);
#pragma unroll
            for (int e = 0; e < 2; ++e)
                gload_lds16(W + Bbase + (long)(e * 32) * K + ko,
                            &Bbuf[s][(e * 256 + tid) * 8]);
        }
    };

    int koff[2];
#pragma unroll
    for (int ks = 0; ks < 2; ++ks)
        koff[ks] = ((ks * 4 + lg) ^ (l15 & 7)) * 8;
    const int aRow = wm * 64 + l15;
    const int bRow = wn * 32 + l15;

    // prologue: tiles 0,1 staged (12 loads); drain tile0, tile1's 6 in flight
    stage(0, 0); stage(0, 1);
    stage(1, 0); stage(1, 1);
    WAITVM6;
    MEMFENCE;
    __builtin_amdgcn_s_barrier();
    MEMFENCE;

    for (int j = 0; j < nT; ++j) {
        const int s = j % 3;
        const u16* ab = Abuf[s];
        const u16* bb = Bbuf[s];
        const bool pre = (j + 2 < nT);

        // phase 0: B frags + A m0,m1
        bf16x8 bfr[2][2];
#pragma unroll
        for (int n = 0; n < 2; ++n)
#pragma unroll
            for (int ks = 0; ks < 2; ++ks)
                bfr[n][ks] = *reinterpret_cast<const bf16x8*>(
                    &bb[(bRow + n * 16) * 64 + koff[ks]]);
        bf16x8 a0[2][2];
#pragma unroll
        for (int mi = 0; mi < 2; ++mi)
#pragma unroll
            for (int ks = 0; ks < 2; ++ks)
                a0[mi][ks] = *reinterpret_cast<const bf16x8*>(
                    &ab[(aRow + mi * 16) * 64 + koff[ks]]);
        if (pre) stage(j + 2, 0);
        MEMFENCE;
        __builtin_amdgcn_s_barrier();
        MEMFENCE;
        __builtin_amdgcn_s_setprio(1);
#pragma unroll
        for (int mi = 0; mi < 2; ++mi)
#pragma unroll
            for (int n = 0; n < 2; ++n)
#pragma unroll
                for (int ks = 0; ks < 2; ++ks)
                    acc[mi][n] = __builtin_amdgcn_mfma_f32_16x16x32_bf16(
                        a0[mi][ks], bfr[n][ks], acc[mi][n], 0, 0, 0);
        __builtin_amdgcn_s_setprio(0);
        MEMFENCE;
        __builtin_amdgcn_s_barrier();
        MEMFENCE;

        // phase 1: A m2,m3
        bf16x8 a1[2][2];
#pragma unroll
        for (int mi = 0; mi < 2; ++mi)
#pragma unroll
            for (int ks = 0; ks < 2; ++ks)
                a1[mi][ks] = *reinterpret_cast<const bf16x8*>(
                    &ab[(aRow + (2 + mi) * 16) * 64 + koff[ks]]);
        if (pre) { stage(j + 2, 1); WAITVM6; }
        else if (j + 1 < nT) { WAITVM0; }
        MEMFENCE;
        __builtin_amdgcn_s_barrier();
        MEMFENCE;
        __builtin_amdgcn_s_setprio(1);
#pragma unroll
        for (int mi = 0; mi < 2; ++mi)
#pragma unroll
            for (int n = 0; n < 2; ++n)
#pragma unroll
                for (int ks = 0; ks < 2; ++ks)
                    acc[2 + mi][n] = __builtin_amdgcn_mfma_f32_16x16x32_bf16(
                        a1[mi][ks], bfr[n][ks], acc[2 + mi][n], 0, 0, 0);
        __builtin_amdgcn_s_setprio(0);
        MEMFENCE;
        __builtin_amdgcn_s_barrier();
        MEMFENCE;
    }

    // epilogue: C/D layout col = lane&15, row = (lane>>4)*4 + reg
    const int crow0 = (int)tileM + wm * 64 + ((lane >> 4) << 2);
    const int ccol0 = (int)tileN + wn * 32 + l15;
#pragma unroll
    for (int m = 0; m < 4; ++m) {
#pragma unroll
        for (int n = 0; n < 2; ++n) {
            const int col = ccol0 + n * 16;
            const float bv = bias[col];
#pragma unroll
            for (int r = 0; r < 4; ++r) {
                const long row = crow0 + m * 16 + r;
                float vv = acc[m][n][r] + bv;
                if (RESID) vv += bf2f(res[row * N + col]);
                if (RELU)  vv = fmaxf(vv, 0.0f);
                C[row * N + col] = f2bf(vv);
            }
        }
    }
}

// ---------------------------------------------------------------- attention
__global__ __launch_bounds__(256) void k_attn_s(
    const u16* __restrict__ qkv, u16* __restrict__ o)
{
    const int wave = threadIdx.x >> 6, lane = threadIdx.x & 63;
    const int g = blockIdx.x * 4 + wave;          // 19968 groups
    const int t = g % 24, bf = g / 24, f = bf % 13, b = bf / 13;
    const int base = b * 624 + f * 24 + t;        // row stride 312
    const int h = lane >> 3, i = (lane >> 2) & 1, c = lane & 3;
    const int off = h * 64 + c * 16;

    float qf[16];
    load16f(qkv + (size_t)(base + i * 312) * 1536 + off, qf);

    float s[2];
#pragma unroll
    for (int j = 0; j < 2; ++j) {
        float d = dot16(qkv + (size_t)(base + j * 312) * 1536 + 512 + off, qf);
        d += __shfl_xor(d, 1);
        d += __shfl_xor(d, 2);
        s[j] = d * 0.125f;
    }
    const float m = fmaxf(s[0], s[1]);
    const float e0 = expf(s[0] - m), e1 = expf(s[1] - m);
    const float inv = 1.0f / (e0 + e1);
    const float p0 = e0 * inv, p1 = e1 * inv;

    float acc[16] = {};
    fma16(qkv + (size_t)base * 1536 + 1024 + off, p0, acc);
    fma16(qkv + (size_t)(base + 312) * 1536 + 1024 + off, p1, acc);

    store16(o + (size_t)(base + i * 312) * 512 + off, acc);
}

__global__ __launch_bounds__(256) void k_attn_f(
    const u16* __restrict__ qkv, u16* __restrict__ o)
{
    const int wave = threadIdx.x >> 6, lane = threadIdx.x & 63;
    const int p = blockIdx.x * 4 + wave;          // 24576 (g,h)
    const int h = p & 7, g = p >> 3;
    const int t = g % 24, bs = g / 24, st = bs % 2, b = bs / 2;
    const int base = b * 624 + st * 312 + t;      // row stride 24
    const int i = lane >> 2, c = lane & 3;
    const int iq = (i < 13) ? i : 12;
    const int off = h * 64 + c * 16;

    float qf[16];
    load16f(qkv + (size_t)(base + iq * 24) * 1536 + off, qf);

    float sc[13];
#pragma unroll
    for (int j = 0; j < 13; ++j) {
        float d = dot16(qkv + (size_t)(base + j * 24) * 1536 + 512 + off, qf);
        d += __shfl_xor(d, 1);
        d += __shfl_xor(d, 2);
        sc[j] = d * 0.125f;
    }
    float m = sc[0];
#pragma unroll
    for (int j = 1; j < 13; ++j) m = fmaxf(m, sc[j]);
    float den = 0.0f;
#pragma unroll
    for (int j = 0; j < 13; ++j) { sc[j] = expf(sc[j] - m); den += sc[j]; }
    const float inv = 1.0f / den;

    float acc[16] = {};
#pragma unroll
    for (int j = 0; j < 13; ++j)
        fma16(qkv + (size_t)(base + j * 24) * 1536 + 1024 + off, sc[j], acc);
#pragma unroll
    for (int e = 0; e < 16; ++e) acc[e] *= inv;

    if (i < 13)
        store16(o + (size_t)(base + i * 24) * 512 + off, acc);
}

// ---------------------------------------------------------------- layernorm
template<bool OUTF32>
__global__ __launch_bounds__(256) void k_ln(
    const u16* __restrict__ in, const float* __restrict__ g,
    const float* __restrict__ be, u16* __restrict__ outb,
    float* __restrict__ outf)
{
    const int row  = blockIdx.x * 4 + (threadIdx.x >> 6);
    const int lane = threadIdx.x & 63;
    const u16* p = in + (size_t)row * 512 + lane * 8;

    uint4 va = *reinterpret_cast<const uint4*>(p);
    uint32_t ua[4] = { va.x, va.y, va.z, va.w };
    float x[8];
#pragma unroll
    for (int i = 0; i < 4; ++i) {
        x[2 * i]     = bf2f((u16)(ua[i] & 0xFFFFu));
        x[2 * i + 1] = bf2f((u16)(ua[i] >> 16));
    }
    float s = 0.f, sq = 0.f;
#pragma unroll
    for (int i = 0; i < 8; ++i) { s += x[i]; sq += x[i] * x[i]; }
#pragma unroll
    for (int off = 32; off; off >>= 1) {
        s  += __shfl_xor(s, off);
        sq += __shfl_xor(sq, off);
    }
    const float mean = s * (1.0f / 512.0f);
    const float var  = sq * (1.0f / 512.0f) - mean * mean;
    const float rstd = rsqrtf(var + 1e-5f);

    const int col = lane * 8;
    float4 g0 = *reinterpret_cast<const float4*>(g + col);
    float4 g1 = *reinterpret_cast<const float4*>(g + col + 4);
    float4 b0 = *reinterpret_cast<const float4*>(be + col);
    float4 b1 = *reinterpret_cast<const float4*>(be + col + 4);
    float gg[8] = { g0.x, g0.y, g0.z, g0.w, g1.x, g1.y, g1.z, g1.w };
    float bb[8] = { b0.x, b0.y, b0.z, b0.w, b1.x, b1.y, b1.z, b1.w };

    float y[8];
#pragma unroll
    for (int i = 0; i < 8; ++i) y[i] = (x[i] - mean) * rstd * gg[i] + bb[i];

    if (OUTF32) {
        float4 o0 = { y[0], y[1], y[2], y[3] };
        float4 o1 = { y[4], y[5], y[6], y[7] };
        reinterpret_cast<float4*>(outf + (size_t)row * 512 + col)[0] = o0;
        reinterpret_cast<float4*>(outf + (size_t)row * 512 + col + 4)[0] = o1;
    } else {
        uint32_t w[4];
#pragma unroll
        for (int i = 0; i < 4; ++i)
            w[i] = (uint32_t)f2bf(y[2 * i]) | ((uint32_t)f2bf(y[2 * i + 1]) << 16);
        uint4 ov = { w[0], w[1], w[2], w[3] };
        *reinterpret_cast<uint4*>(outb + (size_t)row * 512 + col) = ov;
    }
}

// ---------------------------------------------------------------- launch
extern "C" void kernel_launch(void* const* d_in, const int* in_sizes, int n_in,
                              void* d_out, int out_size, void* d_ws, size_t ws_size,
                              hipStream_t stream)
{
    const float* x       = (const float*)d_in[0];
    const float* w_in_s  = (const float*)d_in[1];
    const float* b_in_s  = (const float*)d_in[2];
    const float* w_out_s = (const float*)d_in[3];
    const float* b_out_s = (const float*)d_in[4];
    const float* w_in_f  = (const float*)d_in[5];
    const float* b_in_f  = (const float*)d_in[6];
    const float* w_out_f = (const float*)d_in[7];
    const float* b_out_f = (const float*)d_in[8];
    const float* w1      = (const float*)d_in[9];
    const float* b1      = (const float*)d_in[10];
    const float* w2      = (const float*)d_in[11];
    const float* b2      = (const float*)d_in[12];
    const float* g1      = (const float*)d_in[13];
    const float* be1     = (const float*)d_in[14];
    const float* g2      = (const float*)d_in[15];
    const float* be2     = (const float*)d_in[16];
    const float* g3      = (const float*)d_in[17];
    const float* be3     = (const float*)d_in[18];

    const int R = 39936;               // B*NS*NF*T
    u16* xb   = (u16*)d_ws;            // [R,512]  activation (bf16)
    u16* buf1 = xb + (size_t)R * 512;  // [R,2048] qkv(1536) / ffn hidden
    u16* obuf = buf1 + (size_t)R * 1536;
    u16* wqs  = buf1 + (size_t)R * 2048;   // 6 weights, contiguous
    u16* wos  = wqs + 1536 * 512;
    u16* wqf  = wos + 512 * 512;
    u16* wof  = wqf + 1536 * 512;
    u16* w1b  = wof + 512 * 512;
    u16* w2b  = w1b + 2048 * 512;

    // x -> bf16
    {
        int n4 = (R * 512) / 4;
        k_f32_to_bf16<<<dim3((n4 + 255) / 256), dim3(256), 0, stream>>>(x, xb, n4);
    }
    // all weights -> bf16, one kernel (dst contiguous from wqs; 1048576 f32x4)
    k_convw<<<dim3(1048576 / 256), dim3(256), 0, stream>>>(
        w_in_s, w_out_s, w_in_f, w_out_f, w1, w2, wqs);

    const dim3 blk256(256);
    const dim3 blk512(512);

    // ---- station attention block ----
    k_gemm8p<false, false, 6><<<dim3(936), blk512, 0, stream>>>(
        xb, wqs, b_in_s, nullptr, buf1, R, 1536, 512);
    k_attn_s<<<dim3(19968 / 4), blk256, 0, stream>>>(buf1, obuf);
    k_gemm3s<false, true, 4><<<dim3(624), blk512, 0, stream>>>(
        obuf, wos, b_out_s, xb, xb, R, 512, 512);
    k_ln<false><<<dim3(R / 4), blk256, 0, stream>>>(xb, g1, be1, xb, nullptr);

    // ---- feature attention block ----
    k_gemm8p<false, false, 6><<<dim3(936), blk512, 0, stream>>>(
        xb, wqf, b_in_f, nullptr, buf1, R, 1536, 512);
    k_attn_f<<<dim3(24576 / 4), blk256, 0, stream>>>(buf1, obuf);
    k_gemm3s<false, true, 4><<<dim3(624), blk512, 0, stream>>>(
        obuf, wof, b_out_f, xb, xb, R, 512, 512);
    k_ln<false><<<dim3(R / 4), blk256, 0, stream>>>(xb, g2, be2, xb, nullptr);

    // ---- feed-forward ----
    k_gemm8p<true, false, 8><<<dim3(1248), blk512, 0, stream>>>(
        xb, w1b, b1, nullptr, buf1, R, 2048, 512);
    k_gemm2b<false, true, 8><<<dim3(2496), blk256, 0, stream>>>(
        buf1, w2b, b2, xb, xb, R, 512, 2048);
    k_ln<true><<<dim3(R / 4), blk256, 0, stream>>>(xb, g3, be3, nullptr, (float*)d_out);
}

// Round 11
// 623.025 us; speedup vs baseline: 1.0186x; 1.0186x over previous
//
#include <hip/hip_runtime.h>
#include <stdint.h>

typedef unsigned short u16;
typedef __bf16 bf16x8 __attribute__((ext_vector_type(8)));
typedef float f32x4 __attribute__((ext_vector_type(4)));

#define DEV __device__ __forceinline__

DEV float bf2f(u16 u) {
    union { uint32_t u; float f; } c; c.u = ((uint32_t)u) << 16; return c.f;
}
DEV u16 f2bf(float f) {
    union { float f; uint32_t u; } c; c.f = f;
    uint32_t u = c.u;
    u += 0x7FFFu + ((u >> 16) & 1u);   // round-to-nearest-even
    return (u16)(u >> 16);
}

DEV void gload_lds16(const u16* gp, u16* lp) {
    __builtin_amdgcn_global_load_lds(
        (__attribute__((address_space(1))) u16*)(uintptr_t)gp,
        (__attribute__((address_space(3))) u16*)lp,
        16, 0, 0);
}

#define WAITVM6 asm volatile("s_waitcnt vmcnt(6)" ::: "memory")
#define WAITVM4 asm volatile("s_waitcnt vmcnt(4)" ::: "memory")
#define WAITVM0 asm volatile("s_waitcnt vmcnt(0)" ::: "memory")
#define MEMFENCE asm volatile("" ::: "memory")

// ---- 16-bf16 (32B) helpers -------------------------------------------------
DEV void load16f(const u16* p, float* f) {
    uint4 a = *reinterpret_cast<const uint4*>(p);
    uint4 b = *reinterpret_cast<const uint4*>(p + 8);
    uint32_t w[8] = { a.x, a.y, a.z, a.w, b.x, b.y, b.z, b.w };
#pragma unroll
    for (int k = 0; k < 8; ++k) {
        union { uint32_t u; float f; } lo, hi;
        lo.u = w[k] << 16; hi.u = w[k] & 0xFFFF0000u;
        f[2 * k] = lo.f; f[2 * k + 1] = hi.f;
    }
}
DEV float dot16(const u16* p, const float* q) {
    uint4 a = *reinterpret_cast<const uint4*>(p);
    uint4 b = *reinterpret_cast<const uint4*>(p + 8);
    uint32_t w[8] = { a.x, a.y, a.z, a.w, b.x, b.y, b.z, b.w };
    float d = 0.0f;
#pragma unroll
    for (int k = 0; k < 8; ++k) {
        union { uint32_t u; float f; } lo, hi;
        lo.u = w[k] << 16; hi.u = w[k] & 0xFFFF0000u;
        d += q[2 * k] * lo.f;
        d += q[2 * k + 1] * hi.f;
    }
    return d;
}
DEV void fma16(const u16* p, float pw, float* acc) {
    uint4 a = *reinterpret_cast<const uint4*>(p);
    uint4 b = *reinterpret_cast<const uint4*>(p + 8);
    uint32_t w[8] = { a.x, a.y, a.z, a.w, b.x, b.y, b.z, b.w };
#pragma unroll
    for (int k = 0; k < 8; ++k) {
        union { uint32_t u; float f; } lo, hi;
        lo.u = w[k] << 16; hi.u = w[k] & 0xFFFF0000u;
        acc[2 * k] += pw * lo.f;
        acc[2 * k + 1] += pw * hi.f;
    }
}
DEV void store16(u16* p, const float* y) {
    uint32_t w[8];
#pragma unroll
    for (int k = 0; k < 8; ++k)
        w[k] = (uint32_t)f2bf(y[2 * k]) | ((uint32_t)f2bf(y[2 * k + 1]) << 16);
    uint4 a = { w[0], w[1], w[2], w[3] };
    uint4 b = { w[4], w[5], w[6], w[7] };
    *reinterpret_cast<uint4*>(p) = a;
    *reinterpret_cast<uint4*>(p + 8) = b;
}

// ---------------------------------------------------------------- convert
__global__ __launch_bounds__(256) void k_f32_to_bf16(
    const float* __restrict__ in, u16* __restrict__ out, int n4)
{
    int i = blockIdx.x * 256 + threadIdx.x;
    if (i >= n4) return;
    float4 v = reinterpret_cast<const float4*>(in)[i];
    ushort4 o;
    o.x = f2bf(v.x); o.y = f2bf(v.y); o.z = f2bf(v.z); o.w = f2bf(v.w);
    reinterpret_cast<ushort4*>(out)[i] = o;
}

// all 6 weight tensors -> one contiguous bf16 region (compile-time boundaries)
__global__ __launch_bounds__(256) void k_convw(
    const float* __restrict__ s0, const float* __restrict__ s1,
    const float* __restrict__ s2, const float* __restrict__ s3,
    const float* __restrict__ s4, const float* __restrict__ s5,
    u16* __restrict__ out)
{
    const int i = blockIdx.x * 256 + threadIdx.x;   // f32x4 index, grid exact
    const float4* src;
    int off;
    if      (i <  196608) { src = (const float4*)s0; off = i; }
    else if (i <  262144) { src = (const float4*)s1; off = i - 196608; }
    else if (i <  458752) { src = (const float4*)s2; off = i - 262144; }
    else if (i <  524288) { src = (const float4*)s3; off = i - 458752; }
    else if (i <  786432) { src = (const float4*)s4; off = i - 524288; }
    else                  { src = (const float4*)s5; off = i - 786432; }
    float4 v = src[off];
    ushort4 o;
    o.x = f2bf(v.x); o.y = f2bf(v.y); o.z = f2bf(v.z); o.w = f2bf(v.w);
    reinterpret_cast<ushort4*>(out)[i] = o;
}

// ---------------------------------------------------------------- GEMM 8-phase
// 256x256 tile, BK=64, 512 thr = 8 waves (2M x 4N), per-wave 128x64.
// Used for qkv (N=1536) and FFN1 (N=2048).
template<bool RELU, bool RESID, int NT>
__global__ __launch_bounds__(512, 2) void k_gemm8p(
    const u16* __restrict__ A, const u16* __restrict__ W,
    const float* __restrict__ bias, const u16* __restrict__ res,
    u16* __restrict__ C, int M, int N, int K)
{
    __shared__ __align__(16) u16 Abuf[2][16384];
    __shared__ __align__(16) u16 Bbuf[2][16384];

    const int tid  = threadIdx.x;
    const int lane = tid & 63;
    const int wave = tid >> 6;
    const int wm   = wave >> 2;
    const int wn   = wave & 3;
    const int l15  = lane & 15;
    const int lg   = lane >> 4;

    const int nwg = gridDim.x;
    const int v = (blockIdx.x & 7) * (nwg >> 3) + (blockIdx.x >> 3);
    const long tileM = (long)(v / NT) * 256;
    const long tileN = (long)(v % NT) * 256;

    const int nIter = K >> 7;

    f32x4 acc[8][4] = {};

    const long Abase = (tileM + (tid >> 3)) * (long)K + (((tid & 7) ^ ((tid >> 3) & 7)) << 3);
    const long Bbase = (tileN + (tid >> 3)) * (long)K + (((tid & 7) ^ ((tid >> 3) & 7)) << 3);

    auto stA = [&](int h, int t) {
#pragma unroll
        for (int e = 0; e < 2; ++e)
            gload_lds16(A + Abase + (long)(h * 128 + e * 64) * K + t * 64,
                        &Abuf[t & 1][(h * 1024 + e * 512 + tid) * 8]);
    };
    auto stB = [&](int h, int t) {
#pragma unroll
        for (int e = 0; e < 2; ++e)
            gload_lds16(W + Bbase + (long)(h * 128 + e * 64) * K + t * 64,
                        &Bbuf[t & 1][(h * 1024 + e * 512 + tid) * 8]);
    };

    int koff[2];
#pragma unroll
    for (int ks = 0; ks < 2; ++ks)
        koff[ks] = ((ks * 4 + lg) ^ (l15 & 7)) * 8;
    const int aRow = wm * 128 + l15;
    const int bRow = wn * 64 + l15;

    stA(0, 0); stA(1, 0); stB(0, 0); stB(1, 0); stB(0, 1); stB(1, 1);
    WAITVM4;
    MEMFENCE;
    __builtin_amdgcn_s_barrier();
    MEMFENCE;

    bf16x8 b[4][2];

    for (int j = 0; j < nIter; ++j) {
        const bool pre = (j + 1 < nIter);
        const int E = 2 * j;
#pragma unroll
        for (int ph = 0; ph < 8; ++ph) {
            const int bb = ph >> 2;
            const int q  = ph & 3;
            if (q == 0) {
#pragma unroll
                for (int n = 0; n < 4; ++n)
#pragma unroll
                    for (int ks = 0; ks < 2; ++ks)
                        b[n][ks] = *reinterpret_cast<const bf16x8*>(
                            &Bbuf[bb][(bRow + n * 16) * 64 + koff[ks]]);
            }
            bf16x8 aq[2][2];
#pragma unroll
            for (int mi = 0; mi < 2; ++mi)
#pragma unroll
                for (int ks = 0; ks < 2; ++ks)
                    aq[mi][ks] = *reinterpret_cast<const bf16x8*>(
                        &Abuf[bb][(aRow + (q * 2 + mi) * 16) * 64 + koff[ks]]);
            if (ph == 0) stA(0, E + 1);
            else if (ph == 1) stA(1, E + 1);
            else if (ph == 2) { if (pre) stB(0, E + 2); }
            else if (ph == 3) {
                if (pre) { stB(1, E + 2); WAITVM4; } else { WAITVM0; }
            }
            else if (ph == 4) { if (pre) stA(0, E + 2); }
            else if (ph == 5) { if (pre) stA(1, E + 2); }
            else if (ph == 6) { if (pre) stB(0, E + 3); }
            else {
                if (pre) { stB(1, E + 3); WAITVM4; } else { WAITVM0; }
            }
            MEMFENCE;
            __builtin_amdgcn_s_barrier();
            MEMFENCE;
            __builtin_amdgcn_s_setprio(1);
#pragma unroll
            for (int mi = 0; mi < 2; ++mi)
#pragma unroll
                for (int n = 0; n < 4; ++n)
#pragma unroll
                    for (int ks = 0; ks < 2; ++ks)
                        acc[q * 2 + mi][n] = __builtin_amdgcn_mfma_f32_16x16x32_bf16(
                            aq[mi][ks], b[n][ks], acc[q * 2 + mi][n], 0, 0, 0);
            __builtin_amdgcn_s_setprio(0);
            MEMFENCE;
            __builtin_amdgcn_s_barrier();
            MEMFENCE;
        }
    }

    const int crow0 = (int)tileM + wm * 128 + ((lane >> 4) << 2);
    const int ccol0 = (int)tileN + wn * 64 + l15;
#pragma unroll
    for (int m = 0; m < 8; ++m) {
#pragma unroll
        for (int n = 0; n < 4; ++n) {
            const int col = ccol0 + n * 16;
            const float bv = bias[col];
#pragma unroll
            for (int r = 0; r < 4; ++r) {
                const long row = crow0 + m * 16 + r;
                float vv = acc[m][n][r] + bv;
                if (RESID) vv += bf2f(res[row * N + col]);
                if (RELU)  vv = fmaxf(vv, 0.0f);
                C[row * N + col] = f2bf(vv);
            }
        }
    }
}

// ---------------------------------------------------------------- GEMM 3-slot
// BM=256, BN=128, BK=64, 8 waves (4M x 2N). Used for FFN2 (K=2048).
template<bool RELU, bool RESID, int NT>
__global__ __launch_bounds__(512, 2) void k_gemm3s(
    const u16* __restrict__ A, const u16* __restrict__ W,
    const float* __restrict__ bias, const u16* __restrict__ res,
    u16* __restrict__ C, int M, int N, int K)
{
    __shared__ __align__(16) u16 Abuf[3][16384];
    __shared__ __align__(16) u16 Bbuf[3][8192];

    const int tid  = threadIdx.x;
    const int lane = tid & 63;
    const int wave = tid >> 6;
    const int wm   = wave >> 1;
    const int wn   = wave & 1;
    const int l15  = lane & 15;
    const int lg   = lane >> 4;

    const int nwg = gridDim.x;
    const int v = (blockIdx.x & 7) * (nwg >> 3) + (blockIdx.x >> 3);
    const long tileM = (long)(v / NT) * 256;
    const long tileN = (long)(v % NT) * 128;

    const int nT = K >> 6;

    f32x4 acc[4][4] = {};

    const long Abase = (tileM + (tid >> 3)) * (long)K + (((tid & 7) ^ ((tid >> 3) & 7)) << 3);
    const long Bbase = (tileN + (tid >> 3)) * (long)K + (((tid & 7) ^ ((tid >> 3) & 7)) << 3);

    auto stage = [&](int t, int p) {
        const int s = t % 3;
        const long ko = (long)t * 64;
        if (p == 0) {
#pragma unroll
            for (int e = 0; e < 3; ++e)
                gload_lds16(A + Abase + (long)(e * 64) * K + ko,
                            &Abuf[s][(e * 512 + tid) * 8]);
        } else {
            gload_lds16(A + Abase + (long)192 * K + ko,
                        &Abuf[s][(3 * 512 + tid) * 8]);
#pragma unroll
            for (int e = 0; e < 2; ++e)
                gload_lds16(W + Bbase + (long)(e * 64) * K + ko,
                            &Bbuf[s][(e * 512 + tid) * 8]);
        }
    };

    int koff[2];
#pragma unroll
    for (int ks = 0; ks < 2; ++ks)
        koff[ks] = ((ks * 4 + lg) ^ (l15 & 7)) * 8;
    const int aRow = wm * 64 + l15;
    const int bRow = wn * 64 + l15;

    stage(0, 0); stage(0, 1);
    stage(1, 0); stage(1, 1);
    WAITVM6;
    MEMFENCE;
    __builtin_amdgcn_s_barrier();
    MEMFENCE;

    for (int j = 0; j < nT; ++j) {
        const int s = j % 3;
        const u16* ab = Abuf[s];
        const u16* bb = Bbuf[s];
        const bool pre = (j + 2 < nT);

        bf16x8 bfr[4][2];
#pragma unroll
        for (int n = 0; n < 4; ++n)
#pragma unroll
            for (int ks = 0; ks < 2; ++ks)
                bfr[n][ks] = *reinterpret_cast<const bf16x8*>(
                    &bb[(bRow + n * 16) * 64 + koff[ks]]);
        bf16x8 a0[2][2];
#pragma unroll
        for (int mi = 0; mi < 2; ++mi)
#pragma unroll
            for (int ks = 0; ks < 2; ++ks)
                a0[mi][ks] = *reinterpret_cast<const bf16x8*>(
                    &ab[(aRow + mi * 16) * 64 + koff[ks]]);
        if (pre) stage(j + 2, 0);
        MEMFENCE;
        __builtin_amdgcn_s_barrier();
        MEMFENCE;
        __builtin_amdgcn_s_setprio(1);
#pragma unroll
        for (int mi = 0; mi < 2; ++mi)
#pragma unroll
            for (int n = 0; n < 4; ++n)
#pragma unroll
                for (int ks = 0; ks < 2; ++ks)
                    acc[mi][n] = __builtin_amdgcn_mfma_f32_16x16x32_bf16(
                        a0[mi][ks], bfr[n][ks], acc[mi][n], 0, 0, 0);
        __builtin_amdgcn_s_setprio(0);
        MEMFENCE;
        __builtin_amdgcn_s_barrier();
        MEMFENCE;

        bf16x8 a1[2][2];
#pragma unroll
        for (int mi = 0; mi < 2; ++mi)
#pragma unroll
            for (int ks = 0; ks < 2; ++ks)
                a1[mi][ks] = *reinterpret_cast<const bf16x8*>(
                    &ab[(aRow + (2 + mi) * 16) * 64 + koff[ks]]);
        if (pre) { stage(j + 2, 1); WAITVM6; }
        else if (j + 1 < nT) { WAITVM0; }
        MEMFENCE;
        __builtin_amdgcn_s_barrier();
        MEMFENCE;
        __builtin_amdgcn_s_setprio(1);
#pragma unroll
        for (int mi = 0; mi < 2; ++mi)
#pragma unroll
            for (int n = 0; n < 4; ++n)
#pragma unroll
                for (int ks = 0; ks < 2; ++ks)
                    acc[2 + mi][n] = __builtin_amdgcn_mfma_f32_16x16x32_bf16(
                        a1[mi][ks], bfr[n][ks], acc[2 + mi][n], 0, 0, 0);
        __builtin_amdgcn_s_setprio(0);
        MEMFENCE;
        __builtin_amdgcn_s_barrier();
        MEMFENCE;
    }

    const int crow0 = (int)tileM + wm * 64 + ((lane >> 4) << 2);
    const int ccol0 = (int)tileN + wn * 64 + l15;
#pragma unroll
    for (int m = 0; m < 4; ++m) {
#pragma unroll
        for (int n = 0; n < 4; ++n) {
            const int col = ccol0 + n * 16;
            const float bv = bias[col];
#pragma unroll
            for (int r = 0; r < 4; ++r) {
                const long row = crow0 + m * 16 + r;
                float vv = acc[m][n][r] + bv;
                if (RESID) vv += bf2f(res[row * N + col]);
                if (RELU)  vv = fmaxf(vv, 0.0f);
                C[row * N + col] = f2bf(vv);
            }
        }
    }
}

// ---------------------------------------------------------------- GEMM + LayerNorm
// BM=64, BN=512 (= full row), BK=64, 512 thr = 8 waves (1M x 8N), wave 64x64.
// 2-phase double-buffer (144 KB LDS, uniform 9 gloads/thread/K-tile).
// Epilogue: bias + residual + FULL LayerNorm in-block (block owns whole rows):
// per-lane row partials -> shfl_xor over 16-lane col group -> LDS cross-wave
// reduce -> normalize * g + be -> store (bf16 or f32). Used for proj GEMMs.
template<bool OUTF32>
__global__ __launch_bounds__(512, 1) void k_gemmln(
    const u16* __restrict__ A, const u16* __restrict__ W,
    const float* __restrict__ bias, const u16* __restrict__ res,
    const float* __restrict__ g, const float* __restrict__ be,
    u16* __restrict__ outb, float* __restrict__ outf, int K)
{
    __shared__ __align__(16) u16 As[2][4096];     // 64 x 64
    __shared__ __align__(16) u16 Bs[2][32768];    // 512 x 64
    __shared__ float lnpart[8][64][2];
    __shared__ float lnstat[64][2];

    const int tid  = threadIdx.x;
    const int lane = tid & 63;
    const int wn   = tid >> 6;       // 0..7 = column slice
    const int l15  = lane & 15;
    const int lg   = lane >> 4;

    const int nwg = gridDim.x;       // 624, %8==0
    const int v = (blockIdx.x & 7) * (nwg >> 3) + (blockIdx.x >> 3);
    const long tileM = (long)v * 64;

    const int nT = K >> 6;

    f32x4 acc[4][4] = {};

    // staging: row = tid>>3 (64 A-rows / one of 8 B-row groups), chunk = tid&7
    // pre-swizzled: chunk' = chunk ^ (row&7)
    const long Abase = (tileM + (tid >> 3)) * (long)K + (((tid & 7) ^ ((tid >> 3) & 7)) << 3);
    const long Bbase = ((long)(tid >> 3)) * K + (((tid & 7) ^ ((tid >> 3) & 7)) << 3);

    auto stage = [&](int buf, int t) {
        const long ko = (long)t * 64;
        gload_lds16(A + Abase + ko, &As[buf][tid * 8]);
#pragma unroll
        for (int e = 0; e < 8; ++e)
            gload_lds16(W + Bbase + (long)(e * 64) * K + ko,
                        &Bs[buf][(e * 512 + tid) * 8]);
    };

    int koff[2];
#pragma unroll
    for (int ks = 0; ks < 2; ++ks)
        koff[ks] = ((ks * 4 + lg) ^ (l15 & 7)) * 8;

    auto compute = [&](int buf) {
        bf16x8 a[4][2], b[4][2];
#pragma unroll
        for (int m = 0; m < 4; ++m)
#pragma unroll
            for (int ks = 0; ks < 2; ++ks)
                a[m][ks] = *reinterpret_cast<const bf16x8*>(
                    &As[buf][(m * 16 + l15) * 64 + koff[ks]]);
#pragma unroll
        for (int n = 0; n < 4; ++n)
#pragma unroll
            for (int ks = 0; ks < 2; ++ks)
                b[n][ks] = *reinterpret_cast<const bf16x8*>(
                    &Bs[buf][(wn * 64 + n * 16 + l15) * 64 + koff[ks]]);
        __builtin_amdgcn_s_setprio(1);
#pragma unroll
        for (int m = 0; m < 4; ++m)
#pragma unroll
            for (int n = 0; n < 4; ++n)
#pragma unroll
                for (int ks = 0; ks < 2; ++ks)
                    acc[m][n] = __builtin_amdgcn_mfma_f32_16x16x32_bf16(
                        a[m][ks], b[n][ks], acc[m][n], 0, 0, 0);
        __builtin_amdgcn_s_setprio(0);
    };

    stage(0, 0);
    __syncthreads();
    int cur = 0;
    for (int t = 0; t < nT - 1; ++t) {
        stage(cur ^ 1, t + 1);
        compute(cur);
        __syncthreads();
        cur ^= 1;
    }
    compute(cur);

    // ---- epilogue: bias + residual, row stats, LN
    const int ccol = wn * 64 + l15;
    float bv[4];
#pragma unroll
    for (int n = 0; n < 4; ++n) bv[n] = bias[ccol + n * 16];

    float sp[4][4], sq[4][4];
#pragma unroll
    for (int m = 0; m < 4; ++m)
#pragma unroll
        for (int r = 0; r < 4; ++r) { sp[m][r] = 0.f; sq[m][r] = 0.f; }

#pragma unroll
    for (int m = 0; m < 4; ++m) {
#pragma unroll
        for (int r = 0; r < 4; ++r) {
            const long row = tileM + m * 16 + lg * 4 + r;
#pragma unroll
            for (int n = 0; n < 4; ++n) {
                float xv = acc[m][n][r] + bv[n] + bf2f(res[row * 512 + ccol + n * 16]);
                acc[m][n][r] = xv;
                sp[m][r] += xv;
                sq[m][r] += xv * xv;
            }
        }
    }
    // reduce over the 16-lane column group (same rows, different cols)
#pragma unroll
    for (int e = 1; e < 16; e <<= 1) {
#pragma unroll
        for (int m = 0; m < 4; ++m)
#pragma unroll
            for (int r = 0; r < 4; ++r) {
                sp[m][r] += __shfl_xor(sp[m][r], e);
                sq[m][r] += __shfl_xor(sq[m][r], e);
            }
    }
    if (l15 == 0) {
#pragma unroll
        for (int m = 0; m < 4; ++m)
#pragma unroll
            for (int r = 0; r < 4; ++r) {
                const int rl = m * 16 + lg * 4 + r;
                lnpart[wn][rl][0] = sp[m][r];
                lnpart[wn][rl][1] = sq[m][r];
            }
    }
    __syncthreads();
    if (tid < 64) {
        float s = 0.f, q = 0.f;
#pragma unroll
        for (int w = 0; w < 8; ++w) { s += lnpart[w][tid][0]; q += lnpart[w][tid][1]; }
        const float mean = s * (1.0f / 512.0f);
        const float var  = q * (1.0f / 512.0f) - mean * mean;
        lnstat[tid][0] = mean;
        lnstat[tid][1] = rsqrtf(var + 1e-5f);
    }
    __syncthreads();

    float gv[4], bev[4];
#pragma unroll
    for (int n = 0; n < 4; ++n) { gv[n] = g[ccol + n * 16]; bev[n] = be[ccol + n * 16]; }

#pragma unroll
    for (int m = 0; m < 4; ++m) {
#pragma unroll
        for (int r = 0; r < 4; ++r) {
            const int rl = m * 16 + lg * 4 + r;
            const float mean = lnstat[rl][0];
            const float rstd = lnstat[rl][1];
            const long row = tileM + rl;
#pragma unroll
            for (int n = 0; n < 4; ++n) {
                const float y = (acc[m][n][r] - mean) * rstd * gv[n] + bev[n];
                if (OUTF32) outf[row * 512 + ccol + n * 16] = y;
                else        outb[row * 512 + ccol + n * 16] = f2bf(y);
            }
        }
    }
}

// ---------------------------------------------------------------- attention
__global__ __launch_bounds__(256) void k_attn_s(
    const u16* __restrict__ qkv, u16* __restrict__ o)
{
    const int wave = threadIdx.x >> 6, lane = threadIdx.x & 63;
    const int g = blockIdx.x * 4 + wave;          // 19968 groups
    const int t = g % 24, bf = g / 24, f = bf % 13, b = bf / 13;
    const int base = b * 624 + f * 24 + t;        // row stride 312
    const int h = lane >> 3, i = (lane >> 2) & 1, c = lane & 3;
    const int off = h * 64 + c * 16;

    float qf[16];
    load16f(qkv + (size_t)(base + i * 312) * 1536 + off, qf);

    float s[2];
#pragma unroll
    for (int j = 0; j < 2; ++j) {
        float d = dot16(qkv + (size_t)(base + j * 312) * 1536 + 512 + off, qf);
        d += __shfl_xor(d, 1);
        d += __shfl_xor(d, 2);
        s[j] = d * 0.125f;
    }
    const float m = fmaxf(s[0], s[1]);
    const float e0 = expf(s[0] - m), e1 = expf(s[1] - m);
    const float inv = 1.0f / (e0 + e1);
    const float p0 = e0 * inv, p1 = e1 * inv;

    float acc[16] = {};
    fma16(qkv + (size_t)base * 1536 + 1024 + off, p0, acc);
    fma16(qkv + (size_t)(base + 312) * 1536 + 1024 + off, p1, acc);

    store16(o + (size_t)(base + i * 312) * 512 + off, acc);
}

__global__ __launch_bounds__(256) void k_attn_f(
    const u16* __restrict__ qkv, u16* __restrict__ o)
{
    const int wave = threadIdx.x >> 6, lane = threadIdx.x & 63;
    const int p = blockIdx.x * 4 + wave;          // 24576 (g,h)
    const int h = p & 7, g = p >> 3;
    const int t = g % 24, bs = g / 24, st = bs % 2, b = bs / 2;
    const int base = b * 624 + st * 312 + t;      // row stride 24
    const int i = lane >> 2, c = lane & 3;
    const int iq = (i < 13) ? i : 12;
    const int off = h * 64 + c * 16;

    float qf[16];
    load16f(qkv + (size_t)(base + iq * 24) * 1536 + off, qf);

    float sc[13];
#pragma unroll
    for (int j = 0; j < 13; ++j) {
        float d = dot16(qkv + (size_t)(base + j * 24) * 1536 + 512 + off, qf);
        d += __shfl_xor(d, 1);
        d += __shfl_xor(d, 2);
        sc[j] = d * 0.125f;
    }
    float m = sc[0];
#pragma unroll
    for (int j = 1; j < 13; ++j) m = fmaxf(m, sc[j]);
    float den = 0.0f;
#pragma unroll
    for (int j = 0; j < 13; ++j) { sc[j] = expf(sc[j] - m); den += sc[j]; }
    const float inv = 1.0f / den;

    float acc[16] = {};
#pragma unroll
    for (int j = 0; j < 13; ++j)
        fma16(qkv + (size_t)(base + j * 24) * 1536 + 1024 + off, sc[j], acc);
#pragma unroll
    for (int e = 0; e < 16; ++e) acc[e] *= inv;

    if (i < 13)
        store16(o + (size_t)(base + i * 24) * 512 + off, acc);
}

// ---------------------------------------------------------------- layernorm
template<bool OUTF32>
__global__ __launch_bounds__(256) void k_ln(
    const u16* __restrict__ in, const float* __restrict__ g,
    const float* __restrict__ be, u16* __restrict__ outb,
    float* __restrict__ outf)
{
    const int row  = blockIdx.x * 4 + (threadIdx.x >> 6);
    const int lane = threadIdx.x & 63;
    const u16* p = in + (size_t)row * 512 + lane * 8;

    uint4 va = *reinterpret_cast<const uint4*>(p);
    uint32_t ua[4] = { va.x, va.y, va.z, va.w };
    float x[8];
#pragma unroll
    for (int i = 0; i < 4; ++i) {
        x[2 * i]     = bf2f((u16)(ua[i] & 0xFFFFu));
        x[2 * i + 1] = bf2f((u16)(ua[i] >> 16));
    }
    float s = 0.f, sq = 0.f;
#pragma unroll
    for (int i = 0; i < 8; ++i) { s += x[i]; sq += x[i] * x[i]; }
#pragma unroll
    for (int off = 32; off; off >>= 1) {
        s  += __shfl_xor(s, off);
        sq += __shfl_xor(sq, off);
    }
    const float mean = s * (1.0f / 512.0f);
    const float var  = sq * (1.0f / 512.0f) - mean * mean;
    const float rstd = rsqrtf(var + 1e-5f);

    const int col = lane * 8;
    float4 g0 = *reinterpret_cast<const float4*>(g + col);
    float4 g1 = *reinterpret_cast<const float4*>(g + col + 4);
    float4 b0 = *reinterpret_cast<const float4*>(be + col);
    float4 b1 = *reinterpret_cast<const float4*>(be + col + 4);
    float gg[8] = { g0.x, g0.y, g0.z, g0.w, g1.x, g1.y, g1.z, g1.w };
    float bb[8] = { b0.x, b0.y, b0.z, b0.w, b1.x, b1.y, b1.z, b1.w };

    float y[8];
#pragma unroll
    for (int i = 0; i < 8; ++i) y[i] = (x[i] - mean) * rstd * gg[i] + bb[i];

    if (OUTF32) {
        float4 o0 = { y[0], y[1], y[2], y[3] };
        float4 o1 = { y[4], y[5], y[6], y[7] };
        reinterpret_cast<float4*>(outf + (size_t)row * 512 + col)[0] = o0;
        reinterpret_cast<float4*>(outf + (size_t)row * 512 + col + 4)[0] = o1;
    } else {
        uint32_t w[4];
#pragma unroll
        for (int i = 0; i < 4; ++i)
            w[i] = (uint32_t)f2bf(y[2 * i]) | ((uint32_t)f2bf(y[2 * i + 1]) << 16);
        uint4 ov = { w[0], w[1], w[2], w[3] };
        *reinterpret_cast<uint4*>(outb + (size_t)row * 512 + col) = ov;
    }
}

// ---------------------------------------------------------------- launch
extern "C" void kernel_launch(void* const* d_in, const int* in_sizes, int n_in,
                              void* d_out, int out_size, void* d_ws, size_t ws_size,
                              hipStream_t stream)
{
    const float* x       = (const float*)d_in[0];
    const float* w_in_s  = (const float*)d_in[1];
    const float* b_in_s  = (const float*)d_in[2];
    const float* w_out_s = (const float*)d_in[3];
    const float* b_out_s = (const float*)d_in[4];
    const float* w_in_f  = (const float*)d_in[5];
    const float* b_in_f  = (const float*)d_in[6];
    const float* w_out_f = (const float*)d_in[7];
    const float* b_out_f = (const float*)d_in[8];
    const float* w1      = (const float*)d_in[9];
    const float* b1      = (const float*)d_in[10];
    const float* w2      = (const float*)d_in[11];
    const float* b2      = (const float*)d_in[12];
    const float* g1      = (const float*)d_in[13];
    const float* be1     = (const float*)d_in[14];
    const float* g2      = (const float*)d_in[15];
    const float* be2     = (const float*)d_in[16];
    const float* g3      = (const float*)d_in[17];
    const float* be3     = (const float*)d_in[18];

    const int R = 39936;               // B*NS*NF*T
    u16* xb   = (u16*)d_ws;            // [R,512]  activation (bf16)
    u16* buf1 = xb + (size_t)R * 512;  // [R,2048] qkv(1536) / ffn hidden
    u16* obuf = buf1 + (size_t)R * 1536;
    u16* wqs  = buf1 + (size_t)R * 2048;   // 6 weights, contiguous
    u16* wos  = wqs + 1536 * 512;
    u16* wqf  = wos + 512 * 512;
    u16* wof  = wqf + 1536 * 512;
    u16* w1b  = wof + 512 * 512;
    u16* w2b  = w1b + 2048 * 512;

    // x -> bf16
    {
        int n4 = (R * 512) / 4;
        k_f32_to_bf16<<<dim3((n4 + 255) / 256), dim3(256), 0, stream>>>(x, xb, n4);
    }
    // all weights -> bf16, one kernel (dst contiguous from wqs; 1048576 f32x4)
    k_convw<<<dim3(1048576 / 256), dim3(256), 0, stream>>>(
        w_in_s, w_out_s, w_in_f, w_out_f, w1, w2, wqs);

    const dim3 blk256(256);
    const dim3 blk512(512);

    // ---- station attention block ----
    k_gemm8p<false, false, 6><<<dim3(936), blk512, 0, stream>>>(
        xb, wqs, b_in_s, nullptr, buf1, R, 1536, 512);
    k_attn_s<<<dim3(19968 / 4), blk256, 0, stream>>>(buf1, obuf);
    k_gemmln<false><<<dim3(624), blk512, 0, stream>>>(
        obuf, wos, b_out_s, xb, g1, be1, xb, nullptr, 512);

    // ---- feature attention block ----
    k_gemm8p<false, false, 6><<<dim3(936), blk512, 0, stream>>>(
        xb, wqf, b_in_f, nullptr, buf1, R, 1536, 512);
    k_attn_f<<<dim3(24576 / 4), blk256, 0, stream>>>(buf1, obuf);
    k_gemmln<false><<<dim3(624), blk512, 0, stream>>>(
        obuf, wof, b_out_f, xb, g2, be2, xb, nullptr, 512);

    // ---- feed-forward ----
    k_gemm8p<true, false, 8><<<dim3(1248), blk512, 0, stream>>>(
        xb, w1b, b1, nullptr, buf1, R, 2048, 512);
    k_gemm3s<false, true, 4><<<dim3(624), blk512, 0, stream>>>(
        buf1, w2b, b2, xb, xb, R, 512, 2048);
    k_ln<true><<<dim3(R / 4), blk256, 0, stream>>>(xb, g3, be3, nullptr, (float*)d_out);
}

// Round 12
// 613.870 us; speedup vs baseline: 1.0338x; 1.0149x over previous
//
#include <hip/hip_runtime.h>
#include <stdint.h>

typedef unsigned short u16;
typedef __bf16 bf16x8 __attribute__((ext_vector_type(8)));
typedef float f32x4 __attribute__((ext_vector_type(4)));

#define DEV __device__ __forceinline__

DEV float bf2f(u16 u) {
    union { uint32_t u; float f; } c; c.u = ((uint32_t)u) << 16; return c.f;
}
DEV u16 f2bf(float f) {
    union { float f; uint32_t u; } c; c.f = f;
    uint32_t u = c.u;
    u += 0x7FFFu + ((u >> 16) & 1u);   // round-to-nearest-even
    return (u16)(u >> 16);
}

DEV void gload_lds16(const u16* gp, u16* lp) {
    __builtin_amdgcn_global_load_lds(
        (__attribute__((address_space(1))) u16*)(uintptr_t)gp,
        (__attribute__((address_space(3))) u16*)lp,
        16, 0, 0);
}

#define WAITVM6 asm volatile("s_waitcnt vmcnt(6)" ::: "memory")
#define WAITVM4 asm volatile("s_waitcnt vmcnt(4)" ::: "memory")
#define WAITVM0 asm volatile("s_waitcnt vmcnt(0)" ::: "memory")
#define MEMFENCE asm volatile("" ::: "memory")

// ---- 16-bf16 (32B) helpers -------------------------------------------------
DEV void load16f(const u16* p, float* f) {
    uint4 a = *reinterpret_cast<const uint4*>(p);
    uint4 b = *reinterpret_cast<const uint4*>(p + 8);
    uint32_t w[8] = { a.x, a.y, a.z, a.w, b.x, b.y, b.z, b.w };
#pragma unroll
    for (int k = 0; k < 8; ++k) {
        union { uint32_t u; float f; } lo, hi;
        lo.u = w[k] << 16; hi.u = w[k] & 0xFFFF0000u;
        f[2 * k] = lo.f; f[2 * k + 1] = hi.f;
    }
}
DEV float dot16(const u16* p, const float* q) {
    uint4 a = *reinterpret_cast<const uint4*>(p);
    uint4 b = *reinterpret_cast<const uint4*>(p + 8);
    uint32_t w[8] = { a.x, a.y, a.z, a.w, b.x, b.y, b.z, b.w };
    float d = 0.0f;
#pragma unroll
    for (int k = 0; k < 8; ++k) {
        union { uint32_t u; float f; } lo, hi;
        lo.u = w[k] << 16; hi.u = w[k] & 0xFFFF0000u;
        d += q[2 * k] * lo.f;
        d += q[2 * k + 1] * hi.f;
    }
    return d;
}
DEV void fma16(const u16* p, float pw, float* acc) {
    uint4 a = *reinterpret_cast<const uint4*>(p);
    uint4 b = *reinterpret_cast<const uint4*>(p + 8);
    uint32_t w[8] = { a.x, a.y, a.z, a.w, b.x, b.y, b.z, b.w };
#pragma unroll
    for (int k = 0; k < 8; ++k) {
        union { uint32_t u; float f; } lo, hi;
        lo.u = w[k] << 16; hi.u = w[k] & 0xFFFF0000u;
        acc[2 * k] += pw * lo.f;
        acc[2 * k + 1] += pw * hi.f;
    }
}
DEV void store16(u16* p, const float* y) {
    uint32_t w[8];
#pragma unroll
    for (int k = 0; k < 8; ++k)
        w[k] = (uint32_t)f2bf(y[2 * k]) | ((uint32_t)f2bf(y[2 * k + 1]) << 16);
    uint4 a = { w[0], w[1], w[2], w[3] };
    uint4 b = { w[4], w[5], w[6], w[7] };
    *reinterpret_cast<uint4*>(p) = a;
    *reinterpret_cast<uint4*>(p + 8) = b;
}

// ---------------------------------------------------------------- convert
__global__ __launch_bounds__(256) void k_f32_to_bf16(
    const float* __restrict__ in, u16* __restrict__ out, int n4)
{
    int i = blockIdx.x * 256 + threadIdx.x;
    if (i >= n4) return;
    float4 v = reinterpret_cast<const float4*>(in)[i];
    ushort4 o;
    o.x = f2bf(v.x); o.y = f2bf(v.y); o.z = f2bf(v.z); o.w = f2bf(v.w);
    reinterpret_cast<ushort4*>(out)[i] = o;
}

// all 6 weight tensors -> one contiguous bf16 region (compile-time boundaries)
__global__ __launch_bounds__(256) void k_convw(
    const float* __restrict__ s0, const float* __restrict__ s1,
    const float* __restrict__ s2, const float* __restrict__ s3,
    const float* __restrict__ s4, const float* __restrict__ s5,
    u16* __restrict__ out)
{
    const int i = blockIdx.x * 256 + threadIdx.x;   // f32x4 index, grid exact
    const float4* src;
    int off;
    if      (i <  196608) { src = (const float4*)s0; off = i; }
    else if (i <  262144) { src = (const float4*)s1; off = i - 196608; }
    else if (i <  458752) { src = (const float4*)s2; off = i - 262144; }
    else if (i <  524288) { src = (const float4*)s3; off = i - 458752; }
    else if (i <  786432) { src = (const float4*)s4; off = i - 524288; }
    else                  { src = (const float4*)s5; off = i - 786432; }
    float4 v = src[off];
    ushort4 o;
    o.x = f2bf(v.x); o.y = f2bf(v.y); o.z = f2bf(v.z); o.w = f2bf(v.w);
    reinterpret_cast<ushort4*>(out)[i] = o;
}

// ---------------------------------------------------------------- GEMM 8-phase
// 256x256 tile, BK=64, 512 thr = 8 waves (2M x 4N), per-wave 128x64.
// Used for qkv (N=1536) and FFN1 (N=2048).
template<bool RELU, bool RESID, int NT>
__global__ __launch_bounds__(512, 2) void k_gemm8p(
    const u16* __restrict__ A, const u16* __restrict__ W,
    const float* __restrict__ bias, const u16* __restrict__ res,
    u16* __restrict__ C, int M, int N, int K)
{
    __shared__ __align__(16) u16 Abuf[2][16384];
    __shared__ __align__(16) u16 Bbuf[2][16384];

    const int tid  = threadIdx.x;
    const int lane = tid & 63;
    const int wave = tid >> 6;
    const int wm   = wave >> 2;
    const int wn   = wave & 3;
    const int l15  = lane & 15;
    const int lg   = lane >> 4;

    const int nwg = gridDim.x;
    const int v = (blockIdx.x & 7) * (nwg >> 3) + (blockIdx.x >> 3);
    const long tileM = (long)(v / NT) * 256;
    const long tileN = (long)(v % NT) * 256;

    const int nIter = K >> 7;

    f32x4 acc[8][4] = {};

    const long Abase = (tileM + (tid >> 3)) * (long)K + (((tid & 7) ^ ((tid >> 3) & 7)) << 3);
    const long Bbase = (tileN + (tid >> 3)) * (long)K + (((tid & 7) ^ ((tid >> 3) & 7)) << 3);

    auto stA = [&](int h, int t) {
#pragma unroll
        for (int e = 0; e < 2; ++e)
            gload_lds16(A + Abase + (long)(h * 128 + e * 64) * K + t * 64,
                        &Abuf[t & 1][(h * 1024 + e * 512 + tid) * 8]);
    };
    auto stB = [&](int h, int t) {
#pragma unroll
        for (int e = 0; e < 2; ++e)
            gload_lds16(W + Bbase + (long)(h * 128 + e * 64) * K + t * 64,
                        &Bbuf[t & 1][(h * 1024 + e * 512 + tid) * 8]);
    };

    int koff[2];
#pragma unroll
    for (int ks = 0; ks < 2; ++ks)
        koff[ks] = ((ks * 4 + lg) ^ (l15 & 7)) * 8;
    const int aRow = wm * 128 + l15;
    const int bRow = wn * 64 + l15;

    stA(0, 0); stA(1, 0); stB(0, 0); stB(1, 0); stB(0, 1); stB(1, 1);
    WAITVM4;
    MEMFENCE;
    __builtin_amdgcn_s_barrier();
    MEMFENCE;

    bf16x8 b[4][2];

    for (int j = 0; j < nIter; ++j) {
        const bool pre = (j + 1 < nIter);
        const int E = 2 * j;
#pragma unroll
        for (int ph = 0; ph < 8; ++ph) {
            const int bb = ph >> 2;
            const int q  = ph & 3;
            if (q == 0) {
#pragma unroll
                for (int n = 0; n < 4; ++n)
#pragma unroll
                    for (int ks = 0; ks < 2; ++ks)
                        b[n][ks] = *reinterpret_cast<const bf16x8*>(
                            &Bbuf[bb][(bRow + n * 16) * 64 + koff[ks]]);
            }
            bf16x8 aq[2][2];
#pragma unroll
            for (int mi = 0; mi < 2; ++mi)
#pragma unroll
                for (int ks = 0; ks < 2; ++ks)
                    aq[mi][ks] = *reinterpret_cast<const bf16x8*>(
                        &Abuf[bb][(aRow + (q * 2 + mi) * 16) * 64 + koff[ks]]);
            if (ph == 0) stA(0, E + 1);
            else if (ph == 1) stA(1, E + 1);
            else if (ph == 2) { if (pre) stB(0, E + 2); }
            else if (ph == 3) {
                if (pre) { stB(1, E + 2); WAITVM4; } else { WAITVM0; }
            }
            else if (ph == 4) { if (pre) stA(0, E + 2); }
            else if (ph == 5) { if (pre) stA(1, E + 2); }
            else if (ph == 6) { if (pre) stB(0, E + 3); }
            else {
                if (pre) { stB(1, E + 3); WAITVM4; } else { WAITVM0; }
            }
            MEMFENCE;
            __builtin_amdgcn_s_barrier();
            MEMFENCE;
            __builtin_amdgcn_s_setprio(1);
#pragma unroll
            for (int mi = 0; mi < 2; ++mi)
#pragma unroll
                for (int n = 0; n < 4; ++n)
#pragma unroll
                    for (int ks = 0; ks < 2; ++ks)
                        acc[q * 2 + mi][n] = __builtin_amdgcn_mfma_f32_16x16x32_bf16(
                            aq[mi][ks], b[n][ks], acc[q * 2 + mi][n], 0, 0, 0);
            __builtin_amdgcn_s_setprio(0);
            MEMFENCE;
            __builtin_amdgcn_s_barrier();
            MEMFENCE;
        }
    }

    const int crow0 = (int)tileM + wm * 128 + ((lane >> 4) << 2);
    const int ccol0 = (int)tileN + wn * 64 + l15;
#pragma unroll
    for (int m = 0; m < 8; ++m) {
#pragma unroll
        for (int n = 0; n < 4; ++n) {
            const int col = ccol0 + n * 16;
            const float bv = bias[col];
#pragma unroll
            for (int r = 0; r < 4; ++r) {
                const long row = crow0 + m * 16 + r;
                float vv = acc[m][n][r] + bv;
                if (RESID) vv += bf2f(res[row * N + col]);
                if (RELU)  vv = fmaxf(vv, 0.0f);
                C[row * N + col] = f2bf(vv);
            }
        }
    }
}

// ---------------------------------------------------------------- GEMM 3-slot
// BM=256, BN=128, BK=64, 8 waves (4M x 2N). Used for proj (K=512) and FFN2
// (K=2048). 3-slot ring, counted vmcnt(6).
template<bool RELU, bool RESID, int NT>
__global__ __launch_bounds__(512, 2) void k_gemm3s(
    const u16* __restrict__ A, const u16* __restrict__ W,
    const float* __restrict__ bias, const u16* __restrict__ res,
    u16* __restrict__ C, int M, int N, int K)
{
    __shared__ __align__(16) u16 Abuf[3][16384];
    __shared__ __align__(16) u16 Bbuf[3][8192];

    const int tid  = threadIdx.x;
    const int lane = tid & 63;
    const int wave = tid >> 6;
    const int wm   = wave >> 1;
    const int wn   = wave & 1;
    const int l15  = lane & 15;
    const int lg   = lane >> 4;

    const int nwg = gridDim.x;
    const int v = (blockIdx.x & 7) * (nwg >> 3) + (blockIdx.x >> 3);
    const long tileM = (long)(v / NT) * 256;
    const long tileN = (long)(v % NT) * 128;

    const int nT = K >> 6;

    f32x4 acc[4][4] = {};

    const long Abase = (tileM + (tid >> 3)) * (long)K + (((tid & 7) ^ ((tid >> 3) & 7)) << 3);
    const long Bbase = (tileN + (tid >> 3)) * (long)K + (((tid & 7) ^ ((tid >> 3) & 7)) << 3);

    auto stage = [&](int t, int p) {
        const int s = t % 3;
        const long ko = (long)t * 64;
        if (p == 0) {
#pragma unroll
            for (int e = 0; e < 3; ++e)
                gload_lds16(A + Abase + (long)(e * 64) * K + ko,
                            &Abuf[s][(e * 512 + tid) * 8]);
        } else {
            gload_lds16(A + Abase + (long)192 * K + ko,
                        &Abuf[s][(3 * 512 + tid) * 8]);
#pragma unroll
            for (int e = 0; e < 2; ++e)
                gload_lds16(W + Bbase + (long)(e * 64) * K + ko,
                            &Bbuf[s][(e * 512 + tid) * 8]);
        }
    };

    int koff[2];
#pragma unroll
    for (int ks = 0; ks < 2; ++ks)
        koff[ks] = ((ks * 4 + lg) ^ (l15 & 7)) * 8;
    const int aRow = wm * 64 + l15;
    const int bRow = wn * 64 + l15;

    stage(0, 0); stage(0, 1);
    stage(1, 0); stage(1, 1);
    WAITVM6;
    MEMFENCE;
    __builtin_amdgcn_s_barrier();
    MEMFENCE;

    for (int j = 0; j < nT; ++j) {
        const int s = j % 3;
        const u16* ab = Abuf[s];
        const u16* bb = Bbuf[s];
        const bool pre = (j + 2 < nT);

        bf16x8 bfr[4][2];
#pragma unroll
        for (int n = 0; n < 4; ++n)
#pragma unroll
            for (int ks = 0; ks < 2; ++ks)
                bfr[n][ks] = *reinterpret_cast<const bf16x8*>(
                    &bb[(bRow + n * 16) * 64 + koff[ks]]);
        bf16x8 a0[2][2];
#pragma unroll
        for (int mi = 0; mi < 2; ++mi)
#pragma unroll
            for (int ks = 0; ks < 2; ++ks)
                a0[mi][ks] = *reinterpret_cast<const bf16x8*>(
                    &ab[(aRow + mi * 16) * 64 + koff[ks]]);
        if (pre) stage(j + 2, 0);
        MEMFENCE;
        __builtin_amdgcn_s_barrier();
        MEMFENCE;
        __builtin_amdgcn_s_setprio(1);
#pragma unroll
        for (int mi = 0; mi < 2; ++mi)
#pragma unroll
            for (int n = 0; n < 4; ++n)
#pragma unroll
                for (int ks = 0; ks < 2; ++ks)
                    acc[mi][n] = __builtin_amdgcn_mfma_f32_16x16x32_bf16(
                        a0[mi][ks], bfr[n][ks], acc[mi][n], 0, 0, 0);
        __builtin_amdgcn_s_setprio(0);
        MEMFENCE;
        __builtin_amdgcn_s_barrier();
        MEMFENCE;

        bf16x8 a1[2][2];
#pragma unroll
        for (int mi = 0; mi < 2; ++mi)
#pragma unroll
            for (int ks = 0; ks < 2; ++ks)
                a1[mi][ks] = *reinterpret_cast<const bf16x8*>(
                    &ab[(aRow + (2 + mi) * 16) * 64 + koff[ks]]);
        if (pre) { stage(j + 2, 1); WAITVM6; }
        else if (j + 1 < nT) { WAITVM0; }
        MEMFENCE;
        __builtin_amdgcn_s_barrier();
        MEMFENCE;
        __builtin_amdgcn_s_setprio(1);
#pragma unroll
        for (int mi = 0; mi < 2; ++mi)
#pragma unroll
            for (int n = 0; n < 4; ++n)
#pragma unroll
                for (int ks = 0; ks < 2; ++ks)
                    acc[2 + mi][n] = __builtin_amdgcn_mfma_f32_16x16x32_bf16(
                        a1[mi][ks], bfr[n][ks], acc[2 + mi][n], 0, 0, 0);
        __builtin_amdgcn_s_setprio(0);
        MEMFENCE;
        __builtin_amdgcn_s_barrier();
        MEMFENCE;
    }

    const int crow0 = (int)tileM + wm * 64 + ((lane >> 4) << 2);
    const int ccol0 = (int)tileN + wn * 64 + l15;
#pragma unroll
    for (int m = 0; m < 4; ++m) {
#pragma unroll
        for (int n = 0; n < 4; ++n) {
            const int col = ccol0 + n * 16;
            const float bv = bias[col];
#pragma unroll
            for (int r = 0; r < 4; ++r) {
                const long row = crow0 + m * 16 + r;
                float vv = acc[m][n][r] + bv;
                if (RESID) vv += bf2f(res[row * N + col]);
                if (RELU)  vv = fmaxf(vv, 0.0f);
                C[row * N + col] = f2bf(vv);
            }
        }
    }
}

// ---------------------------------------------------------------- attention
__global__ __launch_bounds__(256) void k_attn_s(
    const u16* __restrict__ qkv, u16* __restrict__ o)
{
    const int wave = threadIdx.x >> 6, lane = threadIdx.x & 63;
    const int g = blockIdx.x * 4 + wave;          // 19968 groups
    const int t = g % 24, bf = g / 24, f = bf % 13, b = bf / 13;
    const int base = b * 624 + f * 24 + t;        // row stride 312
    const int h = lane >> 3, i = (lane >> 2) & 1, c = lane & 3;
    const int off = h * 64 + c * 16;

    float qf[16];
    load16f(qkv + (size_t)(base + i * 312) * 1536 + off, qf);

    float s[2];
#pragma unroll
    for (int j = 0; j < 2; ++j) {
        float d = dot16(qkv + (size_t)(base + j * 312) * 1536 + 512 + off, qf);
        d += __shfl_xor(d, 1);
        d += __shfl_xor(d, 2);
        s[j] = d * 0.125f;
    }
    const float m = fmaxf(s[0], s[1]);
    const float e0 = expf(s[0] - m), e1 = expf(s[1] - m);
    const float inv = 1.0f / (e0 + e1);
    const float p0 = e0 * inv, p1 = e1 * inv;

    float acc[16] = {};
    fma16(qkv + (size_t)base * 1536 + 1024 + off, p0, acc);
    fma16(qkv + (size_t)(base + 312) * 1536 + 1024 + off, p1, acc);

    store16(o + (size_t)(base + i * 312) * 512 + off, acc);
}

__global__ __launch_bounds__(256) void k_attn_f(
    const u16* __restrict__ qkv, u16* __restrict__ o)
{
    const int wave = threadIdx.x >> 6, lane = threadIdx.x & 63;
    const int p = blockIdx.x * 4 + wave;          // 24576 (g,h)
    const int h = p & 7, g = p >> 3;
    const int t = g % 24, bs = g / 24, st = bs % 2, b = bs / 2;
    const int base = b * 624 + st * 312 + t;      // row stride 24
    const int i = lane >> 2, c = lane & 3;
    const int iq = (i < 13) ? i : 12;
    const int off = h * 64 + c * 16;

    float qf[16];
    load16f(qkv + (size_t)(base + iq * 24) * 1536 + off, qf);

    float sc[13];
#pragma unroll
    for (int j = 0; j < 13; ++j) {
        float d = dot16(qkv + (size_t)(base + j * 24) * 1536 + 512 + off, qf);
        d += __shfl_xor(d, 1);
        d += __shfl_xor(d, 2);
        sc[j] = d * 0.125f;
    }
    float m = sc[0];
#pragma unroll
    for (int j = 1; j < 13; ++j) m = fmaxf(m, sc[j]);
    float den = 0.0f;
#pragma unroll
    for (int j = 0; j < 13; ++j) { sc[j] = expf(sc[j] - m); den += sc[j]; }
    const float inv = 1.0f / den;

    float acc[16] = {};
#pragma unroll
    for (int j = 0; j < 13; ++j)
        fma16(qkv + (size_t)(base + j * 24) * 1536 + 1024 + off, sc[j], acc);
#pragma unroll
    for (int e = 0; e < 16; ++e) acc[e] *= inv;

    if (i < 13)
        store16(o + (size_t)(base + i * 24) * 512 + off, acc);
}

// ---------------------------------------------------------------- layernorm
template<bool OUTF32>
__global__ __launch_bounds__(256) void k_ln(
    const u16* __restrict__ in, const float* __restrict__ g,
    const float* __restrict__ be, u16* __restrict__ outb,
    float* __restrict__ outf)
{
    const int row  = blockIdx.x * 4 + (threadIdx.x >> 6);
    const int lane = threadIdx.x & 63;
    const u16* p = in + (size_t)row * 512 + lane * 8;

    uint4 va = *reinterpret_cast<const uint4*>(p);
    uint32_t ua[4] = { va.x, va.y, va.z, va.w };
    float x[8];
#pragma unroll
    for (int i = 0; i < 4; ++i) {
        x[2 * i]     = bf2f((u16)(ua[i] & 0xFFFFu));
        x[2 * i + 1] = bf2f((u16)(ua[i] >> 16));
    }
    float s = 0.f, sq = 0.f;
#pragma unroll
    for (int i = 0; i < 8; ++i) { s += x[i]; sq += x[i] * x[i]; }
#pragma unroll
    for (int off = 32; off; off >>= 1) {
        s  += __shfl_xor(s, off);
        sq += __shfl_xor(sq, off);
    }
    const float mean = s * (1.0f / 512.0f);
    const float var  = sq * (1.0f / 512.0f) - mean * mean;
    const float rstd = rsqrtf(var + 1e-5f);

    const int col = lane * 8;
    float4 g0 = *reinterpret_cast<const float4*>(g + col);
    float4 g1 = *reinterpret_cast<const float4*>(g + col + 4);
    float4 b0 = *reinterpret_cast<const float4*>(be + col);
    float4 b1 = *reinterpret_cast<const float4*>(be + col + 4);
    float gg[8] = { g0.x, g0.y, g0.z, g0.w, g1.x, g1.y, g1.z, g1.w };
    float bb[8] = { b0.x, b0.y, b0.z, b0.w, b1.x, b1.y, b1.z, b1.w };

    float y[8];
#pragma unroll
    for (int i = 0; i < 8; ++i) y[i] = (x[i] - mean) * rstd * gg[i] + bb[i];

    if (OUTF32) {
        float4 o0 = { y[0], y[1], y[2], y[3] };
        float4 o1 = { y[4], y[5], y[6], y[7] };
        reinterpret_cast<float4*>(outf + (size_t)row * 512 + col)[0] = o0;
        reinterpret_cast<float4*>(outf + (size_t)row * 512 + col + 4)[0] = o1;
    } else {
        uint32_t w[4];
#pragma unroll
        for (int i = 0; i < 4; ++i)
            w[i] = (uint32_t)f2bf(y[2 * i]) | ((uint32_t)f2bf(y[2 * i + 1]) << 16);
        uint4 ov = { w[0], w[1], w[2], w[3] };
        *reinterpret_cast<uint4*>(outb + (size_t)row * 512 + col) = ov;
    }
}

// ---------------------------------------------------------------- launch
extern "C" void kernel_launch(void* const* d_in, const int* in_sizes, int n_in,
                              void* d_out, int out_size, void* d_ws, size_t ws_size,
                              hipStream_t stream)
{
    const float* x       = (const float*)d_in[0];
    const float* w_in_s  = (const float*)d_in[1];
    const float* b_in_s  = (const float*)d_in[2];
    const float* w_out_s = (const float*)d_in[3];
    const float* b_out_s = (const float*)d_in[4];
    const float* w_in_f  = (const float*)d_in[5];
    const float* b_in_f  = (const float*)d_in[6];
    const float* w_out_f = (const float*)d_in[7];
    const float* b_out_f = (const float*)d_in[8];
    const float* w1      = (const float*)d_in[9];
    const float* b1      = (const float*)d_in[10];
    const float* w2      = (const float*)d_in[11];
    const float* b2      = (const float*)d_in[12];
    const float* g1      = (const float*)d_in[13];
    const float* be1     = (const float*)d_in[14];
    const float* g2      = (const float*)d_in[15];
    const float* be2     = (const float*)d_in[16];
    const float* g3      = (const float*)d_in[17];
    const float* be3     = (const float*)d_in[18];

    const int R = 39936;               // B*NS*NF*T
    u16* xb   = (u16*)d_ws;            // [R,512]  activation (bf16)
    u16* buf1 = xb + (size_t)R * 512;  // [R,2048] qkv(1536) / ffn hidden
    u16* obuf = buf1 + (size_t)R * 1536;
    u16* wqs  = buf1 + (size_t)R * 2048;   // 6 weights, contiguous
    u16* wos  = wqs + 1536 * 512;
    u16* wqf  = wos + 512 * 512;
    u16* wof  = wqf + 1536 * 512;
    u16* w1b  = wof + 512 * 512;
    u16* w2b  = w1b + 2048 * 512;

    // x -> bf16
    {
        int n4 = (R * 512) / 4;
        k_f32_to_bf16<<<dim3((n4 + 255) / 256), dim3(256), 0, stream>>>(x, xb, n4);
    }
    // all weights -> bf16, one kernel (dst contiguous from wqs; 1048576 f32x4)
    k_convw<<<dim3(1048576 / 256), dim3(256), 0, stream>>>(
        w_in_s, w_out_s, w_in_f, w_out_f, w1, w2, wqs);

    const dim3 blk256(256);
    const dim3 blk512(512);

    // ---- station attention block ----
    k_gemm8p<false, false, 6><<<dim3(936), blk512, 0, stream>>>(
        xb, wqs, b_in_s, nullptr, buf1, R, 1536, 512);
    k_attn_s<<<dim3(19968 / 4), blk256, 0, stream>>>(buf1, obuf);
    k_gemm3s<false, true, 4><<<dim3(624), blk512, 0, stream>>>(
        obuf, wos, b_out_s, xb, xb, R, 512, 512);
    k_ln<false><<<dim3(R / 4), blk256, 0, stream>>>(xb, g1, be1, xb, nullptr);

    // ---- feature attention block ----
    k_gemm8p<false, false, 6><<<dim3(936), blk512, 0, stream>>>(
        xb, wqf, b_in_f, nullptr, buf1, R, 1536, 512);
    k_attn_f<<<dim3(24576 / 4), blk256, 0, stream>>>(buf1, obuf);
    k_gemm3s<false, true, 4><<<dim3(624), blk512, 0, stream>>>(
        obuf, wof, b_out_f, xb, xb, R, 512, 512);
    k_ln<false><<<dim3(R / 4), blk256, 0, stream>>>(xb, g2, be2, xb, nullptr);

    // ---- feed-forward ----
    k_gemm8p<true, false, 8><<<dim3(1248), blk512, 0, stream>>>(
        xb, w1b, b1, nullptr, buf1, R, 2048, 512);
    k_gemm3s<false, true, 4><<<dim3(624), blk512, 0, stream>>>(
        buf1, w2b, b2, xb, xb, R, 512, 2048);
    k_ln<true><<<dim3(R / 4), blk256, 0, stream>>>(xb, g3, be3, nullptr, (float*)d_out);
}